// Round 8
// baseline (19.345 us; speedup 1.0000x reference)
//
#include <hip/hip_runtime.h>

#define G 512
#define N 24
#define DD 12288
#define DIM 64

typedef __fp16 f16x2 __attribute__((ext_vector_type(2)));
typedef __fp16 f16x4 __attribute__((ext_vector_type(4)));
typedef __fp16 f16x8 __attribute__((ext_vector_type(8)));
typedef float  f32x4 __attribute__((ext_vector_type(4)));

#define XSTR 72   // halves per X row: 144 B (16B multiple)
#define HSTR 40   // halves per H unit-row: 80 B (16B multiple)

union PkU { f16x8 v; f16x4 q[2]; f16x2 h2[4]; };

static __device__ __forceinline__ f16x8 pack8(float4 a, float4 b) {
    PkU u;
    u.h2[0] = __builtin_amdgcn_cvt_pkrtz(a.x, a.y);
    u.h2[1] = __builtin_amdgcn_cvt_pkrtz(a.z, a.w);
    u.h2[2] = __builtin_amdgcn_cvt_pkrtz(b.x, b.y);
    u.h2[3] = __builtin_amdgcn_cvt_pkrtz(b.z, b.w);
    return u.v;
}

// One molecule per 256-thread block; wave wv owns unit columns 16wv..16wv+15.
// GEMM1 (H = X @ W^T + b): per wave 2Mt x 1Nt x 2K = 4 MFMA.
// GEMM2 (X' = X + A24 @ H): column-separable -> H wave-private; 2 MFMA.
// Only X' crosses waves: ping-pong Xl, ONE barrier per layer. Tail-MLP
// weights preloaded to registers in the preamble (off the critical tail).
__global__ __launch_bounds__(256, 2)
void gnn_kernel(const int* __restrict__ fp,
                const float* __restrict__ A,
                const float* __restrict__ emb,
                const float* __restrict__ W_fp,
                const float* __restrict__ b_fp,
                const float* __restrict__ W_out,
                const float* __restrict__ b_out,
                const float* __restrict__ W_prop,
                const float* __restrict__ b_prop,
                float* __restrict__ out)
{
    const int t  = threadIdx.x;
    const int l  = t & 63;
    const int wv = t >> 6;     // 0..3: unit-tile owner
    const int p  = l & 15;
    const int q4 = l >> 4;
    const int tt = t & 63;     // tail row index (valid address for all waves)
    const int gq = blockIdx.x;
    const long srow = (long)gq * N;

    __shared__ __align__(16) __fp16 Xl[2][32][XSTR];  // 9.2 KB ping-pong X (f16)
    __shared__ __align__(16) __fp16 Hl[4][16][HSTR];  // 5.1 KB per-wave H
    __shared__ float molv[DIM];
    __shared__ float ybuf[DIM];

    // ---- embedding -> Xl[0]: wave wv loads atoms 6wv..6wv+5; zero pad rows ----
    #pragma unroll
    for (int i = 0; i < 6; ++i) {
        int a = 6 * wv + i;
        int f = fp[gq * N + a];                    // wave-uniform -> s_load
        Xl[0][a][l] = (__fp16)emb[(long)f * DIM + l];
    }
    Xl[0][24 + 2 * wv][l] = (__fp16)0.f;
    Xl[0][25 + 2 * wv][l] = (__fp16)0.f;

    // ---- f32 master X direct from global (exact; no barrier dependency) ----
    // C-layout: row = 16mt+4q4+reg, col = 16wv+p
    f32x4 xacc[2];
    #pragma unroll
    for (int mt = 0; mt < 2; ++mt)
        #pragma unroll
        for (int reg = 0; reg < 4; ++reg) {
            int row = 16 * mt + 4 * q4 + reg;
            float v = 0.f;
            if (row < N) {
                int f = fp[gq * N + row];              // 4B gather, L1-hot
                v = emb[(long)f * DIM + 16 * wv + p];
            }
            xacc[mt][reg] = v;
        }

    // ---- A24 fragments (A-op: row = 16mt+p, k = 8q4+i), zero-masked pad ----
    f16x8 a24[2];
    #pragma unroll
    for (int mt = 0; mt < 2; ++mt) {
        int r = 16 * mt + p;
        if (r < N && q4 < 3) {
            const float* src = A + (srow + r) * (long)DD + srow + 8 * q4;
            a24[mt] = pack8(*(const float4*)src, *(const float4*)(src + 4));
        } else {
            f16x8 z = { (__fp16)0, (__fp16)0, (__fp16)0, (__fp16)0,
                        (__fp16)0, (__fp16)0, (__fp16)0, (__fp16)0 };
            a24[mt] = z;
        }
    }

    // ---- W fragments + biases, own 16-unit tile (B-op: col=p, k=32s+8q4+i) ----
    f16x8 wf[3][2];
    float bias[3];
    #pragma unroll
    for (int lyr = 0; lyr < 3; ++lyr) {
        #pragma unroll
        for (int s = 0; s < 2; ++s) {
            const float* src = W_fp + lyr * DIM * DIM + (16 * wv + p) * DIM + 32 * s + 8 * q4;
            wf[lyr][s] = pack8(*(const float4*)src, *(const float4*)(src + 4));
        }
        bias[lyr] = b_fp[lyr * DIM + 16 * wv + p];
    }

    // ---- tail MLP weights -> registers (off the critical tail path) ----
    float4 wo0r[16], wo1r[16];
    #pragma unroll
    for (int k4 = 0; k4 < 16; ++k4) {
        wo0r[k4] = *(const float4*)(W_out + tt * DIM + 4 * k4);
        wo1r[k4] = *(const float4*)(W_out + DIM * DIM + tt * DIM + 4 * k4);
    }
    const float bo0 = b_out[tt];
    const float bo1 = b_out[DIM + tt];
    const float wp0 = W_prop[tt];
    const float wp1 = W_prop[DIM + tt];

    __syncthreads();   // X complete

    // ---- 3 message-passing layers, one barrier each ----
    #pragma unroll
    for (int lyr = 0; lyr < 3; ++lyr) {
        const int cur = lyr & 1;

        f32x4 acc0 = { bias[lyr], bias[lyr], bias[lyr], bias[lyr] };
        f32x4 acc1 = acc0;
        #pragma unroll
        for (int s = 0; s < 2; ++s) {
            f16x8 xa0 = *(const f16x8*)(&Xl[cur][p][32 * s + 8 * q4]);
            f16x8 xa1 = *(const f16x8*)(&Xl[cur][16 + p][32 * s + 8 * q4]);
            acc0 = __builtin_amdgcn_mfma_f32_16x16x32_f16(xa0, wf[lyr][s], acc0, 0, 0, 0);
            acc1 = __builtin_amdgcn_mfma_f32_16x16x32_f16(xa1, wf[lyr][s], acc1, 0, 0, 0);
        }

        // relu -> wave-private Hl[wv][unit p][atom]: packed b64 stores
        {
            PkU u0, u1;
            u0.h2[0] = __builtin_amdgcn_cvt_pkrtz(fmaxf(acc0[0], 0.f), fmaxf(acc0[1], 0.f));
            u0.h2[1] = __builtin_amdgcn_cvt_pkrtz(fmaxf(acc0[2], 0.f), fmaxf(acc0[3], 0.f));
            u1.h2[0] = __builtin_amdgcn_cvt_pkrtz(fmaxf(acc1[0], 0.f), fmaxf(acc1[1], 0.f));
            u1.h2[1] = __builtin_amdgcn_cvt_pkrtz(fmaxf(acc1[2], 0.f), fmaxf(acc1[3], 0.f));
            *(f16x4*)(&Hl[wv][p][4 * q4])      = u0.q[0];   // atoms 4q4..4q4+3
            *(f16x4*)(&Hl[wv][p][16 + 4 * q4]) = u1.q[0];   // atoms 16+4q4..+3
        }

        // GEMM2 (intra-wave): B-frag = H[k=8q4+i][col p] contiguous b128
        f16x8 hb = *(const f16x8*)(&Hl[wv][p][8 * q4]);
        xacc[0] = __builtin_amdgcn_mfma_f32_16x16x32_f16(a24[0], hb, xacc[0], 0, 0, 0);
        xacc[1] = __builtin_amdgcn_mfma_f32_16x16x32_f16(a24[1], hb, xacc[1], 0, 0, 0);

        // publish X' (own cols) into the other buffer; barrier
        if (lyr < 2) {
            const int nxt = cur ^ 1;
            #pragma unroll
            for (int mt = 0; mt < 2; ++mt)
                #pragma unroll
                for (int reg = 0; reg < 4; ++reg)
                    Xl[nxt][16 * mt + 4 * q4 + reg][16 * wv + p] = (__fp16)xacc[mt][reg];
            __syncthreads();
        }
    }

    // ---- segment sum (pad rows are exactly 0 -> unconditional) ----
    float part = (xacc[0][0] + xacc[0][1]) + (xacc[0][2] + xacc[0][3])
               + (xacc[1][0] + xacc[1][1]) + (xacc[1][2] + xacc[1][3]);
    part += __shfl_xor(part, 16, 64);
    part += __shfl_xor(part, 32, 64);
    if (l < 16) molv[16 * wv + l] = part;
    __syncthreads();

    // ---- output MLP + property head, wave 0, weights already in registers ----
    if (t < DIM) {
        float accy = bo0;
        #pragma unroll
        for (int k4 = 0; k4 < 16; ++k4) {
            float4 mv = *(const float4*)(&molv[4 * k4]);   // uniform broadcast
            accy += wo0r[k4].x * mv.x + wo0r[k4].y * mv.y
                  + wo0r[k4].z * mv.z + wo0r[k4].w * mv.w;
        }
        ybuf[t] = fmaxf(accy, 0.f);

        float accz = bo1;
        #pragma unroll
        for (int k4 = 0; k4 < 16; ++k4) {
            float4 yv = *(const float4*)(&ybuf[4 * k4]);   // uniform broadcast
            accz += wo1r[k4].x * yv.x + wo1r[k4].y * yv.y
                  + wo1r[k4].z * yv.z + wo1r[k4].w * yv.w;
        }
        float z = fmaxf(accz, 0.f);

        float t0 = z * wp0;
        float t1 = z * wp1;
        #pragma unroll
        for (int off = 1; off < 64; off <<= 1) {
            t0 += __shfl_xor(t0, off, 64);
            t1 += __shfl_xor(t1, off, 64);
        }
        if (t == 0) {
            out[gq * 2 + 0] = t0 + b_prop[0];
            out[gq * 2 + 1] = t1 + b_prop[1];
        }
    }
}

extern "C" void kernel_launch(void* const* d_in, const int* in_sizes, int n_in,
                              void* d_out, int out_size, void* d_ws, size_t ws_size,
                              hipStream_t stream) {
    const int*   fp     = (const int*)  d_in[0];
    // d_in[1] segment_ids: implied by block index
    const float* A      = (const float*)d_in[2];
    const float* emb    = (const float*)d_in[3];
    const float* W_fp   = (const float*)d_in[4];
    const float* b_fp   = (const float*)d_in[5];
    const float* W_out  = (const float*)d_in[6];
    const float* b_out  = (const float*)d_in[7];
    const float* W_prop = (const float*)d_in[8];
    const float* b_prop = (const float*)d_in[9];
    float* outp = (float*)d_out;

    gnn_kernel<<<G, 256, 0, stream>>>(fp, A, emb, W_fp, b_fp,
                                      W_out, b_out, W_prop, b_prop, outp);
}

// Round 9
// 12.344 us; speedup vs baseline: 1.5672x; 1.5672x over previous
//
#include <hip/hip_runtime.h>

#define G 512
#define N 24
#define DD 12288
#define DIM 64

typedef __fp16 f16x2 __attribute__((ext_vector_type(2)));
typedef __fp16 f16x4 __attribute__((ext_vector_type(4)));
typedef __fp16 f16x8 __attribute__((ext_vector_type(8)));
typedef float  f32x4 __attribute__((ext_vector_type(4)));

#define XSTR 72   // halves per X row: 144 B (16B multiple)
#define HSTR 40   // halves per H unit-row: 80 B (16B multiple)

union PkU { f16x8 v; f16x4 q[2]; f16x2 h2[4]; };

static __device__ __forceinline__ f16x8 pack8(float4 a, float4 b) {
    PkU u;
    u.h2[0] = __builtin_amdgcn_cvt_pkrtz(a.x, a.y);
    u.h2[1] = __builtin_amdgcn_cvt_pkrtz(a.z, a.w);
    u.h2[2] = __builtin_amdgcn_cvt_pkrtz(b.x, b.y);
    u.h2[3] = __builtin_amdgcn_cvt_pkrtz(b.z, b.w);
    return u.v;
}

// One molecule per 256-thread block; wave wv owns unit columns 16wv..16wv+15.
// GEMM1 (H = X @ W^T + b): per wave 2Mt x 1Nt x 2K = 4 MFMA.
// GEMM2 (X' = X + A24 @ H): column-separable -> H is wave-private; 2 MFMA.
// Only X' crosses waves: ping-pong Xl buffer, ONE barrier per layer.
// (Round-9 = exact round-7 revert: R8's 128-VGPR tail preload spilled.)
__global__ __launch_bounds__(256, 2)
void gnn_kernel(const int* __restrict__ fp,
                const float* __restrict__ A,
                const float* __restrict__ emb,
                const float* __restrict__ W_fp,
                const float* __restrict__ b_fp,
                const float* __restrict__ W_out,
                const float* __restrict__ b_out,
                const float* __restrict__ W_prop,
                const float* __restrict__ b_prop,
                float* __restrict__ out)
{
    const int t  = threadIdx.x;
    const int l  = t & 63;
    const int wv = t >> 6;     // 0..3: unit-tile owner
    const int p  = l & 15;
    const int q4 = l >> 4;
    const int gq = blockIdx.x;
    const long srow = (long)gq * N;

    __shared__ __align__(16) __fp16 Xl[2][32][XSTR];  // 9.2 KB ping-pong X (f16)
    __shared__ __align__(16) __fp16 Hl[4][16][HSTR];  // 5.1 KB per-wave H
    __shared__ float molv[DIM];
    __shared__ float ybuf[DIM];

    // ---- embedding -> Xl[0]: wave wv loads atoms 6wv..6wv+5; zero pad rows ----
    #pragma unroll
    for (int i = 0; i < 6; ++i) {
        int a = 6 * wv + i;
        int f = fp[gq * N + a];                    // wave-uniform -> s_load
        Xl[0][a][l] = (__fp16)emb[(long)f * DIM + l];
    }
    Xl[0][24 + 2 * wv][l] = (__fp16)0.f;
    Xl[0][25 + 2 * wv][l] = (__fp16)0.f;

    // ---- A24 fragments (A-op: row = 16mt+p, k = 8q4+i), zero-masked pad ----
    f16x8 a24[2];
    #pragma unroll
    for (int mt = 0; mt < 2; ++mt) {
        int r = 16 * mt + p;
        if (r < N && q4 < 3) {
            const float* src = A + (srow + r) * (long)DD + srow + 8 * q4;
            a24[mt] = pack8(*(const float4*)src, *(const float4*)(src + 4));
        } else {
            f16x8 z = { (__fp16)0, (__fp16)0, (__fp16)0, (__fp16)0,
                        (__fp16)0, (__fp16)0, (__fp16)0, (__fp16)0 };
            a24[mt] = z;
        }
    }

    // ---- W fragments + biases, own 16-unit tile only (B-op: col=p, k=32s+8q4+i) ----
    f16x8 wf[3][2];
    float bias[3];
    #pragma unroll
    for (int lyr = 0; lyr < 3; ++lyr) {
        #pragma unroll
        for (int s = 0; s < 2; ++s) {
            const float* src = W_fp + lyr * DIM * DIM + (16 * wv + p) * DIM + 32 * s + 8 * q4;
            wf[lyr][s] = pack8(*(const float4*)src, *(const float4*)(src + 4));
        }
        bias[lyr] = b_fp[lyr * DIM + 16 * wv + p];
    }

    __syncthreads();   // X complete

    // ---- f32 master X in C-layout: row = 16mt+4q4+reg, col = 16wv+p ----
    f32x4 xacc[2];
    #pragma unroll
    for (int mt = 0; mt < 2; ++mt)
        #pragma unroll
        for (int reg = 0; reg < 4; ++reg)
            xacc[mt][reg] = (float)Xl[0][16 * mt + 4 * q4 + reg][16 * wv + p];

    // ---- 3 message-passing layers, one barrier each ----
    #pragma unroll
    for (int lyr = 0; lyr < 3; ++lyr) {
        const int cur = lyr & 1;

        f32x4 acc0 = { bias[lyr], bias[lyr], bias[lyr], bias[lyr] };
        f32x4 acc1 = acc0;
        #pragma unroll
        for (int s = 0; s < 2; ++s) {
            f16x8 xa0 = *(const f16x8*)(&Xl[cur][p][32 * s + 8 * q4]);
            f16x8 xa1 = *(const f16x8*)(&Xl[cur][16 + p][32 * s + 8 * q4]);
            acc0 = __builtin_amdgcn_mfma_f32_16x16x32_f16(xa0, wf[lyr][s], acc0, 0, 0, 0);
            acc1 = __builtin_amdgcn_mfma_f32_16x16x32_f16(xa1, wf[lyr][s], acc1, 0, 0, 0);
        }

        // relu -> wave-private Hl[wv][unit p][atom]: packed b64 stores
        {
            PkU u0, u1;
            u0.h2[0] = __builtin_amdgcn_cvt_pkrtz(fmaxf(acc0[0], 0.f), fmaxf(acc0[1], 0.f));
            u0.h2[1] = __builtin_amdgcn_cvt_pkrtz(fmaxf(acc0[2], 0.f), fmaxf(acc0[3], 0.f));
            u1.h2[0] = __builtin_amdgcn_cvt_pkrtz(fmaxf(acc1[0], 0.f), fmaxf(acc1[1], 0.f));
            u1.h2[1] = __builtin_amdgcn_cvt_pkrtz(fmaxf(acc1[2], 0.f), fmaxf(acc1[3], 0.f));
            *(f16x4*)(&Hl[wv][p][4 * q4])      = u0.q[0];   // atoms 4q4..4q4+3
            *(f16x4*)(&Hl[wv][p][16 + 4 * q4]) = u1.q[0];   // atoms 16+4q4..+3
        }

        // GEMM2 (intra-wave): B-frag = H[k=8q4+i][col p] contiguous b128
        f16x8 hb = *(const f16x8*)(&Hl[wv][p][8 * q4]);
        xacc[0] = __builtin_amdgcn_mfma_f32_16x16x32_f16(a24[0], hb, xacc[0], 0, 0, 0);
        xacc[1] = __builtin_amdgcn_mfma_f32_16x16x32_f16(a24[1], hb, xacc[1], 0, 0, 0);

        // publish X' (own cols) into the other buffer; barrier
        if (lyr < 2) {
            const int nxt = cur ^ 1;
            #pragma unroll
            for (int mt = 0; mt < 2; ++mt)
                #pragma unroll
                for (int reg = 0; reg < 4; ++reg)
                    Xl[nxt][16 * mt + 4 * q4 + reg][16 * wv + p] = (__fp16)xacc[mt][reg];
            __syncthreads();
        }
    }

    // ---- segment sum (pad rows are exactly 0 -> unconditional) ----
    float part = (xacc[0][0] + xacc[0][1]) + (xacc[0][2] + xacc[0][3])
               + (xacc[1][0] + xacc[1][1]) + (xacc[1][2] + xacc[1][3]);
    part += __shfl_xor(part, 16, 64);
    part += __shfl_xor(part, 32, 64);
    if (l < 16) molv[16 * wv + l] = part;
    __syncthreads();

    // ---- output MLP + property head, wave 0 only ----
    if (t < DIM) {
        float accy = b_out[t];
        const float* Wr0 = W_out + t * DIM;
        #pragma unroll
        for (int k4 = 0; k4 < 16; ++k4) {
            float4 wr = *(const float4*)(Wr0 + 4 * k4);
            float4 mv = *(const float4*)(&molv[4 * k4]);   // uniform broadcast
            accy += wr.x * mv.x + wr.y * mv.y + wr.z * mv.z + wr.w * mv.w;
        }
        ybuf[t] = fmaxf(accy, 0.f);

        float accz = b_out[DIM + t];
        const float* Wr1 = W_out + DIM * DIM + t * DIM;
        #pragma unroll
        for (int k4 = 0; k4 < 16; ++k4) {
            float4 wr = *(const float4*)(Wr1 + 4 * k4);
            float4 yv = *(const float4*)(&ybuf[4 * k4]);   // uniform broadcast
            accz += wr.x * yv.x + wr.y * yv.y + wr.z * yv.z + wr.w * yv.w;
        }
        float z = fmaxf(accz, 0.f);

        float t0 = z * W_prop[t];
        float t1 = z * W_prop[DIM + t];
        #pragma unroll
        for (int off = 1; off < 64; off <<= 1) {
            t0 += __shfl_xor(t0, off, 64);
            t1 += __shfl_xor(t1, off, 64);
        }
        if (t == 0) {
            out[gq * 2 + 0] = t0 + b_prop[0];
            out[gq * 2 + 1] = t1 + b_prop[1];
        }
    }
}

extern "C" void kernel_launch(void* const* d_in, const int* in_sizes, int n_in,
                              void* d_out, int out_size, void* d_ws, size_t ws_size,
                              hipStream_t stream) {
    const int*   fp     = (const int*)  d_in[0];
    // d_in[1] segment_ids: implied by block index
    const float* A      = (const float*)d_in[2];
    const float* emb    = (const float*)d_in[3];
    const float* W_fp   = (const float*)d_in[4];
    const float* b_fp   = (const float*)d_in[5];
    const float* W_out  = (const float*)d_in[6];
    const float* b_out  = (const float*)d_in[7];
    const float* W_prop = (const float*)d_in[8];
    const float* b_prop = (const float*)d_in[9];
    float* outp = (float*)d_out;

    gnn_kernel<<<G, 256, 0, stream>>>(fp, A, emb, W_fp, b_fp,
                                      W_out, b_out, W_prop, b_prop, outp);
}